// Round 6
// baseline (112.703 us; speedup 1.0000x reference)
//
#include <hip/hip_runtime.h>
#include <climits>
#include <math.h>

using short8 = __attribute__((ext_vector_type(8))) short;
using f32x4  = __attribute__((ext_vector_type(4))) float;
typedef _Float16 half8 __attribute__((ext_vector_type(8)));
typedef unsigned short u16;

#define BATCH 8192
#define TDIM  384
#define GDIM  256

// ---------- helpers ----------
__device__ __forceinline__ u16 f2bf(float x) {
  unsigned u = __float_as_uint(x);
  unsigned r = (u + 0x7FFFu + ((u >> 16) & 1u)) >> 16;  // RTNE
  return (u16)r;
}

__device__ __forceinline__ void gload16(u16* lds, const u16* src) {
  __builtin_amdgcn_global_load_lds(
      (const __attribute__((address_space(1))) void*)src,
      (__attribute__((address_space(3))) void*)lds, 16, 0, 0);
}

// ---------- 1. normalize text rows -> fp16; also init key arrays ----------
__global__ void prep_text(const float* __restrict__ text, u16* __restrict__ tH,
                          int* __restrict__ gMax, int* __restrict__ gMin) {
  if (blockIdx.x < 32) {
    const int i = blockIdx.x * 256 + threadIdx.x;
    gMax[i] = INT_MIN;
    gMin[i] = INT_MAX;
  }
  const int lane = threadIdx.x & 63;
  const int wid  = threadIdx.x >> 6;
  const int row  = blockIdx.x * 4 + wid;
  const float* x = text + row * TDIM;
  float v[6];
  float ss = 0.f;
#pragma unroll
  for (int q = 0; q < 6; ++q) { v[q] = x[lane + q * 64]; ss += v[q] * v[q]; }
#pragma unroll
  for (int m = 1; m < 64; m <<= 1) ss += __shfl_xor(ss, m);
  const float scale = 1.0f / fmaxf(sqrtf(ss), 1e-12f);
#pragma unroll
  for (int q = 0; q < 6; ++q) {
    _Float16 h = (_Float16)(v[q] * scale);
    tH[row * TDIM + lane + q * 64] = *(u16*)&h;
  }
}

// ---------- 2. fp32 -> bf16 for graph and W ----------
__global__ void cvt_all(const float* __restrict__ graph, const float* __restrict__ W,
                        u16* __restrict__ gHi, u16* __restrict__ wHi) {
  int i = blockIdx.x * 256 + threadIdx.x;
  if (i < 524288) {
    float4 v = ((const float4*)graph)[i];
    ushort4 o; o.x = f2bf(v.x); o.y = f2bf(v.y); o.z = f2bf(v.z); o.w = f2bf(v.w);
    ((ushort4*)gHi)[i] = o;
  } else {
    int j = i - 524288;
    if (j < 24576) {
      float4 v = ((const float4*)W)[j];
      ushort4 o; o.x = f2bf(v.x); o.y = f2bf(v.y); o.z = f2bf(v.z); o.w = f2bf(v.w);
      ((ushort4*)wHi)[j] = o;
    }
  }
}

// ---------- 3. g = graph @ W^T + b  (bf16 MFMA, raw output; norm fused later) ----------
__global__ __launch_bounds__(256) void gemm1(const u16* __restrict__ gHi,
                                             const u16* __restrict__ wHi,
                                             const float* __restrict__ bias,
                                             float* __restrict__ g) {
  __shared__ u16 sA[128 * 32];
  __shared__ u16 sB[128 * 32];
  const int tid = threadIdx.x;
  const int lane = tid & 63, wid = tid >> 6;
  const int l15 = lane & 15, l4 = lane >> 4;
  const int wrb = (wid >> 1) * 64, wcb = (wid & 1) * 64;
  const int iBase = blockIdx.x * 128, jBase = blockIdx.y * 128;
  const int sRow = tid >> 2, sS = (tid & 3) * 8;

  f32x4 acc[4][4];
#pragma unroll
  for (int i = 0; i < 4; ++i)
#pragma unroll
    for (int j = 0; j < 4; ++j) acc[i][j] = (f32x4){0.f, 0.f, 0.f, 0.f};

  for (int ks = 0; ks < GDIM / 32; ++ks) {
    const int kB = ks * 32;
    __syncthreads();
    gload16(&sA[tid * 8],        gHi + (size_t)(iBase + sRow) * GDIM + kB + sS);
    gload16(&sA[2048 + tid * 8], gHi + (size_t)(iBase + 64 + sRow) * GDIM + kB + sS);
    gload16(&sB[tid * 8],        wHi + (size_t)(jBase + sRow) * GDIM + kB + sS);
    gload16(&sB[2048 + tid * 8], wHi + (size_t)(jBase + 64 + sRow) * GDIM + kB + sS);
    __syncthreads();
    short8 a[4], b[4];
#pragma unroll
    for (int f = 0; f < 4; ++f) {
      a[f] = *(const short8*)&sA[(wrb + f * 16 + l15) * 32 + l4 * 8];
      b[f] = *(const short8*)&sB[(wcb + f * 16 + l15) * 32 + l4 * 8];
    }
#pragma unroll
    for (int i = 0; i < 4; ++i)
#pragma unroll
      for (int j = 0; j < 4; ++j)
        acc[i][j] = __builtin_amdgcn_mfma_f32_16x16x32_bf16(a[i], b[j], acc[i][j], 0, 0, 0);
  }
#pragma unroll
  for (int j = 0; j < 4; ++j) {
    const int col = jBase + wcb + j * 16 + l15;
    const float bv = bias[col];
#pragma unroll
    for (int i = 0; i < 4; ++i)
#pragma unroll
      for (int r = 0; r < 4; ++r) {
        const int row = iBase + wrb + i * 16 + l4 * 4 + r;
        g[(size_t)row * TDIM + col] = acc[i][j][r] + bv;
      }
  }
}

// ---------- 4. sim = t@t.T triangle, 256x128 tiles, fp16, fused argmax/argmin ----
// 4 waves, each owns 64x128 (acc[4][8]). Tiles (bi in [0,32), bj in [2bi,64));
// below-diagonal duplicates inside crossing tiles are harmless (max/min
// idempotent), so every tile folds both directions unconditionally.
// 3-slot LDS rotation + counted vmcnt(6); XOR source swizzle; setprio on MFMA.
__global__ __launch_bounds__(256, 2) void simk(const u16* __restrict__ tH,
                                               int* __restrict__ gMax,
                                               int* __restrict__ gMin) {
  __shared__ u16 sA[3][8192];   // 256 rows x 32
  __shared__ u16 sB[3][4096];   // 128 rows x 32
  const int tid = threadIdx.x;
  const int lane = tid & 63, wid = tid >> 6;
  const int l15 = lane & 15, l4 = lane >> 4;
  const int wrb = wid * 64;
  const int sRow = tid >> 2;
  const int cg = (((tid & 3) ^ (sRow & 3)) * 8);  // swizzled source col-group

  // ---- XCD-chunked bijective swizzle: 1056 = 8 x 132 ----
  const int b = blockIdx.x;
  const int id = (b & 7) * 132 + (b >> 3);

  // ---- decode (bi, bj): off(bi) = bi*(65-bi) ----
  int bi = (int)((65.0 - sqrt(4225.0 - 4.0 * (double)id)) * 0.5);
  if (bi < 0) bi = 0;
  while (bi * (65 - bi) > id) --bi;
  while ((bi + 1) * (65 - (bi + 1)) <= id) ++bi;
  const int bj = 2 * bi + (id - bi * (65 - bi));
  const int rBase = bi * 256, cBase = bj * 128;
  const bool mayDiag = ((bj >> 1) == bi);

  const u16* aS = tH + (size_t)rBase * TDIM;
  const u16* bS = tH + (size_t)cBase * TDIM;

  f32x4 acc[4][8];
#pragma unroll
  for (int i = 0; i < 4; ++i)
#pragma unroll
    for (int j = 0; j < 8; ++j) acc[i][j] = (f32x4){0.f, 0.f, 0.f, 0.f};

#define STAGE_T(kt, slot) do {                                                     \
    const int kB_ = (kt) * 32;                                                     \
    gload16(&sA[slot][tid * 8],        aS + (size_t)sRow * TDIM + kB_ + cg);       \
    gload16(&sA[slot][2048 + tid * 8], aS + (size_t)(sRow + 64) * TDIM + kB_ + cg);\
    gload16(&sA[slot][4096 + tid * 8], aS + (size_t)(sRow + 128) * TDIM + kB_ + cg);\
    gload16(&sA[slot][6144 + tid * 8], aS + (size_t)(sRow + 192) * TDIM + kB_ + cg);\
    gload16(&sB[slot][tid * 8],        bS + (size_t)sRow * TDIM + kB_ + cg);       \
    gload16(&sB[slot][2048 + tid * 8], bS + (size_t)(sRow + 64) * TDIM + kB_ + cg);\
  } while (0)

  STAGE_T(0, 0);
  STAGE_T(1, 1);

#pragma unroll
  for (int t = 0; t < 12; ++t) {
    if (t == 11) { asm volatile("s_waitcnt vmcnt(0)" ::: "memory"); }
    else         { asm volatile("s_waitcnt vmcnt(6)" ::: "memory"); }
    __builtin_amdgcn_s_barrier();
    asm volatile("" ::: "memory");

    const int slot = t % 3;
    half8 a[4], b8[8];
#pragma unroll
    for (int f = 0; f < 4; ++f) {
      const int ar = wrb + f * 16 + l15;
      a[f] = *(const half8*)&sA[slot][ar * 32 + ((l4 ^ (ar & 3)) * 8)];
    }
#pragma unroll
    for (int j = 0; j < 8; ++j) {
      const int br = j * 16 + l15;
      b8[j] = *(const half8*)&sB[slot][br * 32 + ((l4 ^ (br & 3)) * 8)];
    }
    if (t < 10) STAGE_T(t + 2, (t + 2) % 3);  // slot was last read at t-1; post-barrier safe

    __builtin_amdgcn_s_setprio(1);
#pragma unroll
    for (int i = 0; i < 4; ++i)
#pragma unroll
      for (int j = 0; j < 8; ++j)
        acc[i][j] = __builtin_amdgcn_mfma_f32_16x16x32_f16(a[i], b8[j], acc[i][j], 0, 0, 0);
    __builtin_amdgcn_s_setprio(0);
  }
#undef STAGE_T

  // ---- fold tile into packed int keys ----
  int keyMax[16], keyMin[16], keyMaxT[8], keyMinT[8];
#pragma unroll
  for (int s = 0; s < 16; ++s) { keyMax[s] = INT_MIN; keyMin[s] = INT_MAX; }
#pragma unroll
  for (int j = 0; j < 8; ++j) { keyMaxT[j] = INT_MIN; keyMinT[j] = INT_MAX; }

#pragma unroll
  for (int i = 0; i < 4; ++i)
#pragma unroll
    for (int j = 0; j < 8; ++j) {
      const int cIdx = cBase + j * 16 + l15;
#pragma unroll
      for (int r = 0; r < 4; ++r) {
        const int grow = rBase + wrb + i * 16 + l4 * 4 + r;
        const int qv = (int)(acc[i][j][r] * 131072.0f);
        int km = qv * 8192 + (8191 - cIdx);
        int kn = qv * 8192 + cIdx;
        int kmT = qv * 8192 + (8191 - grow);
        int knT = qv * 8192 + grow;
        if (mayDiag && grow == cIdx) {
          km = 8191 - cIdx; kn = INT_MAX;       // diag: max sees 0, min sees +inf
          kmT = 8191 - grow; knT = INT_MAX;
        }
        const int s = i * 4 + r;
        keyMax[s] = max(keyMax[s], km);
        keyMin[s] = min(keyMin[s], kn);
        keyMaxT[j] = max(keyMaxT[j], kmT);
        keyMinT[j] = min(keyMinT[j], knT);
      }
    }

  // direct: reduce across 16 column-lanes, atomics per row
#pragma unroll
  for (int s = 0; s < 16; ++s) {
    int km = keyMax[s], kn = keyMin[s];
#pragma unroll
    for (int m = 1; m < 16; m <<= 1) {
      km = max(km, __shfl_xor(km, m));
      kn = min(kn, __shfl_xor(kn, m));
    }
    if (l15 == 0) {
      const int row = rBase + wrb + (s >> 2) * 16 + l4 * 4 + (s & 3);
      atomicMax(&gMax[row], km);
      atomicMin(&gMin[row], kn);
    }
  }
  // transposed: reduce across the 4 l4-groups, atomics per column
#pragma unroll
  for (int j = 0; j < 8; ++j) {
    int km = keyMaxT[j], kn = keyMinT[j];
    km = max(km, __shfl_xor(km, 16)); kn = min(kn, __shfl_xor(kn, 16));
    km = max(km, __shfl_xor(km, 32)); kn = min(kn, __shfl_xor(kn, 32));
    if (l4 == 0) {
      const int colp = cBase + j * 16 + l15;
      atomicMax(&gMax[colp], km);
      atomicMin(&gMin[colp], kn);
    }
  }
}

// ---------- 5. per-row triplet loss from raw g (norm fused via cosine) ----------
__global__ void loss_rows(const float* __restrict__ g, const int* __restrict__ gMax,
                          const int* __restrict__ gMin, float* __restrict__ losses) {
  const int lane = threadIdx.x & 63;
  const int wid  = threadIdx.x >> 6;
  const int row  = blockIdx.x * 4 + wid;
  const int pos = 8191 - (gMax[row] & 8191);
  const int neg = gMin[row] & 8191;
  const float* ga = g + (size_t)row * TDIM;
  const float* gp = g + (size_t)pos * TDIM;
  const float* gn = g + (size_t)neg * TDIM;
  float ssa = 0.f, ssp = 0.f, ssn = 0.f, dap = 0.f, dan = 0.f;
#pragma unroll
  for (int q = 0; q < 6; ++q) {
    const int o = lane + q * 64;
    const float a = ga[o], p = gp[o], n = gn[o];
    ssa += a * a; ssp += p * p; ssn += n * n;
    dap += a * p; dan += a * n;
  }
#pragma unroll
  for (int m = 1; m < 64; m <<= 1) {
    ssa += __shfl_xor(ssa, m);
    ssp += __shfl_xor(ssp, m);
    ssn += __shfl_xor(ssn, m);
    dap += __shfl_xor(dap, m);
    dan += __shfl_xor(dan, m);
  }
  if (lane == 0) {
    const float pd = 2.0f - 2.0f * dap / sqrtf(ssa * ssp);
    const float nd = 2.0f - 2.0f * dan / sqrtf(ssa * ssn);
    losses[row] = fmaxf(pd - nd + 0.5f, 0.0f);
  }
}

// ---------- 6. deterministic mean ----------
__global__ void final_reduce(const float* __restrict__ losses, float* __restrict__ out) {
  __shared__ float red[256];
  float s = 0.f;
  for (int i = threadIdx.x; i < BATCH; i += 256) s += losses[i];
  red[threadIdx.x] = s;
  __syncthreads();
  for (int w = 128; w > 0; w >>= 1) {
    if (threadIdx.x < w) red[threadIdx.x] += red[threadIdx.x + w];
    __syncthreads();
  }
  if (threadIdx.x == 0) out[0] = red[0] * (1.0f / (float)BATCH);
}

extern "C" void kernel_launch(void* const* d_in, const int* in_sizes, int n_in,
                              void* d_out, int out_size, void* d_ws, size_t ws_size,
                              hipStream_t stream) {
  const float* graph = (const float*)d_in[0];
  const float* text  = (const float*)d_in[1];
  const float* W     = (const float*)d_in[2];
  const float* bias  = (const float*)d_in[3];
  float* out = (float*)d_out;
  char* ws = (char*)d_ws;

  u16*  tH     = (u16*)(ws);                 // 8192*384*2  = 6291456
  u16*  gHi    = (u16*)(ws + 6291456);       // 8192*256*2  = 4194304
  u16*  wHi    = (u16*)(ws + 10485760);      // 384*256*2   = 196608
  float* g     = (float*)(ws + 10682368);    // 8192*384*4  = 12582912
  int*  gMax   = (int*)(ws + 23265280);      // 32768
  int*  gMin   = (int*)(ws + 23298048);      // 32768
  float* losses = (float*)(ws + 23330816);   // 32768

  prep_text<<<dim3(2048), dim3(256), 0, stream>>>(text, tH, gMax, gMin);
  cvt_all<<<dim3(2144), dim3(256), 0, stream>>>(graph, W, gHi, wHi);
  gemm1<<<dim3(64, 3), dim3(256), 0, stream>>>(gHi, wHi, bias, g);
  simk<<<dim3(1056), dim3(256), 0, stream>>>(tH, gMax, gMin);
  loss_rows<<<dim3(2048), dim3(256), 0, stream>>>(g, gMax, gMin, losses);
  final_reduce<<<dim3(1), dim3(256), 0, stream>>>(losses, out);
}

// Round 7
// 103.648 us; speedup vs baseline: 1.0874x; 1.0874x over previous
//
#include <hip/hip_runtime.h>
#include <climits>

using short8 = __attribute__((ext_vector_type(8))) short;
using f32x4  = __attribute__((ext_vector_type(4))) float;
typedef _Float16 half8 __attribute__((ext_vector_type(8)));
typedef unsigned short u16;

#define BATCH 8192
#define TDIM  384
#define GDIM  256

// ---------- helpers ----------
__device__ __forceinline__ u16 f2bf(float x) {
  unsigned u = __float_as_uint(x);
  unsigned r = (u + 0x7FFFu + ((u >> 16) & 1u)) >> 16;  // RTNE
  return (u16)r;
}

__device__ __forceinline__ void gload16(u16* lds, const u16* src) {
  __builtin_amdgcn_global_load_lds(
      (const __attribute__((address_space(1))) void*)src,
      (__attribute__((address_space(3))) void*)lds, 16, 0, 0);
}

// bank-swizzle slot permutation: rows within each residue class mod 4 also
// rotate, so a 16-consecutive-row ds_read_b128 hits every bank exactly 8x.
__device__ __forceinline__ int cswz(int r) { return (r + (r >> 2)) & 3; }

// ---------- 1. normalize text rows -> fp16; also init key arrays ----------
__global__ void prep_text(const float* __restrict__ text, u16* __restrict__ tH,
                          int* __restrict__ gMax, int* __restrict__ gMin) {
  if (blockIdx.x < 32) {
    const int i = blockIdx.x * 256 + threadIdx.x;
    gMax[i] = INT_MIN;
    gMin[i] = INT_MAX;
  }
  const int lane = threadIdx.x & 63;
  const int wid  = threadIdx.x >> 6;
  const int row  = blockIdx.x * 4 + wid;
  const float* x = text + row * TDIM;
  float v[6];
  float ss = 0.f;
#pragma unroll
  for (int q = 0; q < 6; ++q) { v[q] = x[lane + q * 64]; ss += v[q] * v[q]; }
#pragma unroll
  for (int m = 1; m < 64; m <<= 1) ss += __shfl_xor(ss, m);
  const float scale = 1.0f / fmaxf(sqrtf(ss), 1e-12f);
#pragma unroll
  for (int q = 0; q < 6; ++q) {
    _Float16 h = (_Float16)(v[q] * scale);
    tH[row * TDIM + lane + q * 64] = *(u16*)&h;
  }
}

// ---------- 2. fp32 -> bf16 for graph and W ----------
__global__ void cvt_all(const float* __restrict__ graph, const float* __restrict__ W,
                        u16* __restrict__ gHi, u16* __restrict__ wHi) {
  int i = blockIdx.x * 256 + threadIdx.x;
  if (i < 524288) {
    float4 v = ((const float4*)graph)[i];
    ushort4 o; o.x = f2bf(v.x); o.y = f2bf(v.y); o.z = f2bf(v.z); o.w = f2bf(v.w);
    ((ushort4*)gHi)[i] = o;
  } else {
    int j = i - 524288;
    if (j < 24576) {
      float4 v = ((const float4*)W)[j];
      ushort4 o; o.x = f2bf(v.x); o.y = f2bf(v.y); o.z = f2bf(v.z); o.w = f2bf(v.w);
      ((ushort4*)wHi)[j] = o;
    }
  }
}

// ---------- 3. g = graph @ W^T + b  (bf16 MFMA, raw output; norm fused later) ----------
__global__ __launch_bounds__(256) void gemm1(const u16* __restrict__ gHi,
                                             const u16* __restrict__ wHi,
                                             const float* __restrict__ bias,
                                             float* __restrict__ g) {
  __shared__ u16 sA[128 * 32];
  __shared__ u16 sB[128 * 32];
  const int tid = threadIdx.x;
  const int lane = tid & 63, wid = tid >> 6;
  const int l15 = lane & 15, l4 = lane >> 4;
  const int wrb = (wid >> 1) * 64, wcb = (wid & 1) * 64;
  const int iBase = blockIdx.x * 128, jBase = blockIdx.y * 128;
  const int sRow = tid >> 2, sS = (tid & 3) * 8;

  f32x4 acc[4][4];
#pragma unroll
  for (int i = 0; i < 4; ++i)
#pragma unroll
    for (int j = 0; j < 4; ++j) acc[i][j] = (f32x4){0.f, 0.f, 0.f, 0.f};

  for (int ks = 0; ks < GDIM / 32; ++ks) {
    const int kB = ks * 32;
    __syncthreads();
    gload16(&sA[tid * 8],        gHi + (size_t)(iBase + sRow) * GDIM + kB + sS);
    gload16(&sA[2048 + tid * 8], gHi + (size_t)(iBase + 64 + sRow) * GDIM + kB + sS);
    gload16(&sB[tid * 8],        wHi + (size_t)(jBase + sRow) * GDIM + kB + sS);
    gload16(&sB[2048 + tid * 8], wHi + (size_t)(jBase + 64 + sRow) * GDIM + kB + sS);
    __syncthreads();
    short8 a[4], b[4];
#pragma unroll
    for (int f = 0; f < 4; ++f) {
      a[f] = *(const short8*)&sA[(wrb + f * 16 + l15) * 32 + l4 * 8];
      b[f] = *(const short8*)&sB[(wcb + f * 16 + l15) * 32 + l4 * 8];
    }
#pragma unroll
    for (int i = 0; i < 4; ++i)
#pragma unroll
      for (int j = 0; j < 4; ++j)
        acc[i][j] = __builtin_amdgcn_mfma_f32_16x16x32_bf16(a[i], b[j], acc[i][j], 0, 0, 0);
  }
#pragma unroll
  for (int j = 0; j < 4; ++j) {
    const int col = jBase + wcb + j * 16 + l15;
    const float bv = bias[col];
#pragma unroll
    for (int i = 0; i < 4; ++i)
#pragma unroll
      for (int r = 0; r < 4; ++r) {
        const int row = iBase + wrb + i * 16 + l4 * 4 + r;
        g[(size_t)row * TDIM + col] = acc[i][j][r] + bv;
      }
  }
}

// ---------- 4. sim = t@t.T triangle, 256x128 tiles, fp16, fused argmax/argmin ----
// Supertile order (4bi x 8bj panels ~1.6 MB <= 4 MB XCD L2) + bijective
// XCD-chunked swizzle (1056 = 8*132). 4 waves of 64x128 (acc[4][8]).
// 3-slot LDS rotation, counted vmcnt(6) (never 0 in steady state), stage
// issued immediately post-barrier, conflict-free c(r) bank swizzle
// (pre-swizzled global source + swizzled ds_read; LDS dest linear).
__global__ __launch_bounds__(256, 2) void simk(const u16* __restrict__ tH,
                                               int* __restrict__ gMax,
                                               int* __restrict__ gMin) {
  __shared__ u16 sA[3][8192];   // 256 rows x 32
  __shared__ u16 sB[3][4096];   // 128 rows x 32
  const int tid = threadIdx.x;
  const int lane = tid & 63, wid = tid >> 6;
  const int l15 = lane & 15, l4 = lane >> 4;
  const int wrb = wid * 64;
  const int sRow = tid >> 2;
  const int cg = (((tid & 3) ^ cswz(sRow)) * 8);  // pre-swizzled source col-group

  // ---- XCD-chunked bijective swizzle: 1056 = 8 x 132 ----
  const int b = blockIdx.x;
  const int id = (b & 7) * 132 + (b >> 3);

  // ---- supertile-major decode over the triangle bj >= 2*bi ----
  // SI row: diag supertile (20 tiles: a=0..3 with 8,6,4,2) + (7-SI) full (32).
  int SI = 0, rem = id;
  for (; SI < 8; ++SI) {
    const int rc = 20 + (7 - SI) * 32;
    if (rem < rc) break;
    rem -= rc;
  }
  int bi, bj;
  if (rem < 20) {
    int a, bb;
    if (rem < 8)       { a = 0; bb = rem; }
    else if (rem < 14) { a = 1; bb = 2 + (rem - 8); }
    else if (rem < 18) { a = 2; bb = 4 + (rem - 14); }
    else               { a = 3; bb = 6 + (rem - 18); }
    bi = SI * 4 + a;
    bj = SI * 8 + bb;
  } else {
    const int r2 = rem - 20;
    const int sj = SI + 1 + (r2 >> 5);
    const int l = r2 & 31;
    bi = SI * 4 + (l >> 3);
    bj = sj * 8 + (l & 7);
  }
  const int rBase = bi * 256, cBase = bj * 128;
  const bool mayDiag = ((bj >> 1) == bi);

  const u16* aS = tH + (size_t)rBase * TDIM;
  const u16* bS = tH + (size_t)cBase * TDIM;

  f32x4 acc[4][8];
#pragma unroll
  for (int i = 0; i < 4; ++i)
#pragma unroll
    for (int j = 0; j < 8; ++j) acc[i][j] = (f32x4){0.f, 0.f, 0.f, 0.f};

#define STAGE_T(kt, slot) do {                                                     \
    const int kB_ = (kt) * 32;                                                     \
    gload16(&sA[slot][tid * 8],        aS + (size_t)sRow * TDIM + kB_ + cg);       \
    gload16(&sA[slot][2048 + tid * 8], aS + (size_t)(sRow + 64) * TDIM + kB_ + cg);\
    gload16(&sA[slot][4096 + tid * 8], aS + (size_t)(sRow + 128) * TDIM + kB_ + cg);\
    gload16(&sA[slot][6144 + tid * 8], aS + (size_t)(sRow + 192) * TDIM + kB_ + cg);\
    gload16(&sB[slot][tid * 8],        bS + (size_t)sRow * TDIM + kB_ + cg);       \
    gload16(&sB[slot][2048 + tid * 8], bS + (size_t)(sRow + 64) * TDIM + kB_ + cg);\
  } while (0)

  STAGE_T(0, 0);
  STAGE_T(1, 1);

#pragma unroll
  for (int t = 0; t < 12; ++t) {
    if (t == 11) { asm volatile("s_waitcnt vmcnt(0)" ::: "memory"); }
    else         { asm volatile("s_waitcnt vmcnt(6)" ::: "memory"); }
    __builtin_amdgcn_s_barrier();
    asm volatile("" ::: "memory");

    // issue next-next stage FIRST: slot (t+2)%3 was last read at t-1, safe
    // post-barrier; loads get a full phase of latency cover.
    if (t < 10) STAGE_T(t + 2, (t + 2) % 3);

    const int slot = t % 3;
    half8 a[4], b8[8];
#pragma unroll
    for (int f = 0; f < 4; ++f) {
      const int ar = wrb + f * 16 + l15;
      a[f] = *(const half8*)&sA[slot][ar * 32 + ((l4 ^ cswz(ar)) * 8)];
    }
#pragma unroll
    for (int j = 0; j < 8; ++j) {
      const int br = j * 16 + l15;
      b8[j] = *(const half8*)&sB[slot][br * 32 + ((l4 ^ cswz(br)) * 8)];
    }

    __builtin_amdgcn_s_setprio(1);
#pragma unroll
    for (int i = 0; i < 4; ++i)
#pragma unroll
      for (int j = 0; j < 8; ++j)
        acc[i][j] = __builtin_amdgcn_mfma_f32_16x16x32_f16(a[i], b8[j], acc[i][j], 0, 0, 0);
    __builtin_amdgcn_s_setprio(0);
  }
#undef STAGE_T

  // ---- fold tile into packed int keys ----
  int keyMax[16], keyMin[16], keyMaxT[8], keyMinT[8];
#pragma unroll
  for (int s = 0; s < 16; ++s) { keyMax[s] = INT_MIN; keyMin[s] = INT_MAX; }
#pragma unroll
  for (int j = 0; j < 8; ++j) { keyMaxT[j] = INT_MIN; keyMinT[j] = INT_MAX; }

#pragma unroll
  for (int i = 0; i < 4; ++i)
#pragma unroll
    for (int j = 0; j < 8; ++j) {
      const int cIdx = cBase + j * 16 + l15;
#pragma unroll
      for (int r = 0; r < 4; ++r) {
        const int grow = rBase + wrb + i * 16 + l4 * 4 + r;
        const int qv = (int)(acc[i][j][r] * 131072.0f);
        int km = qv * 8192 + (8191 - cIdx);
        int kn = qv * 8192 + cIdx;
        int kmT = qv * 8192 + (8191 - grow);
        int knT = qv * 8192 + grow;
        if (mayDiag && grow == cIdx) {
          km = 8191 - cIdx; kn = INT_MAX;       // diag: max sees 0, min sees +inf
          kmT = 8191 - grow; knT = INT_MAX;
        }
        const int s = i * 4 + r;
        keyMax[s] = max(keyMax[s], km);
        keyMin[s] = min(keyMin[s], kn);
        keyMaxT[j] = max(keyMaxT[j], kmT);
        keyMinT[j] = min(keyMinT[j], knT);
      }
    }

  // direct: reduce across 16 column-lanes, atomics per row
#pragma unroll
  for (int s = 0; s < 16; ++s) {
    int km = keyMax[s], kn = keyMin[s];
#pragma unroll
    for (int m = 1; m < 16; m <<= 1) {
      km = max(km, __shfl_xor(km, m));
      kn = min(kn, __shfl_xor(kn, m));
    }
    if (l15 == 0) {
      const int row = rBase + wrb + (s >> 2) * 16 + l4 * 4 + (s & 3);
      atomicMax(&gMax[row], km);
      atomicMin(&gMin[row], kn);
    }
  }
  // transposed: reduce across the 4 l4-groups, atomics per column
#pragma unroll
  for (int j = 0; j < 8; ++j) {
    int km = keyMaxT[j], kn = keyMinT[j];
    km = max(km, __shfl_xor(km, 16)); kn = min(kn, __shfl_xor(kn, 16));
    km = max(km, __shfl_xor(km, 32)); kn = min(kn, __shfl_xor(kn, 32));
    if (l4 == 0) {
      const int colp = cBase + j * 16 + l15;
      atomicMax(&gMax[colp], km);
      atomicMin(&gMin[colp], kn);
    }
  }
}

// ---------- 5. per-row triplet loss from raw g (norm fused via cosine) ----------
__global__ void loss_rows(const float* __restrict__ g, const int* __restrict__ gMax,
                          const int* __restrict__ gMin, float* __restrict__ losses) {
  const int lane = threadIdx.x & 63;
  const int wid  = threadIdx.x >> 6;
  const int row  = blockIdx.x * 4 + wid;
  const int pos = 8191 - (gMax[row] & 8191);
  const int neg = gMin[row] & 8191;
  const float* ga = g + (size_t)row * TDIM;
  const float* gp = g + (size_t)pos * TDIM;
  const float* gn = g + (size_t)neg * TDIM;
  float ssa = 0.f, ssp = 0.f, ssn = 0.f, dap = 0.f, dan = 0.f;
#pragma unroll
  for (int q = 0; q < 6; ++q) {
    const int o = lane + q * 64;
    const float a = ga[o], p = gp[o], n = gn[o];
    ssa += a * a; ssp += p * p; ssn += n * n;
    dap += a * p; dan += a * n;
  }
#pragma unroll
  for (int m = 1; m < 64; m <<= 1) {
    ssa += __shfl_xor(ssa, m);
    ssp += __shfl_xor(ssp, m);
    ssn += __shfl_xor(ssn, m);
    dap += __shfl_xor(dap, m);
    dan += __shfl_xor(dan, m);
  }
  if (lane == 0) {
    const float pd = 2.0f - 2.0f * dap / sqrtf(ssa * ssp);
    const float nd = 2.0f - 2.0f * dan / sqrtf(ssa * ssn);
    losses[row] = fmaxf(pd - nd + 0.5f, 0.0f);
  }
}

// ---------- 6. deterministic mean ----------
__global__ void final_reduce(const float* __restrict__ losses, float* __restrict__ out) {
  __shared__ float red[256];
  float s = 0.f;
  for (int i = threadIdx.x; i < BATCH; i += 256) s += losses[i];
  red[threadIdx.x] = s;
  __syncthreads();
  for (int w = 128; w > 0; w >>= 1) {
    if (threadIdx.x < w) red[threadIdx.x] += red[threadIdx.x + w];
    __syncthreads();
  }
  if (threadIdx.x == 0) out[0] = red[0] * (1.0f / (float)BATCH);
}

extern "C" void kernel_launch(void* const* d_in, const int* in_sizes, int n_in,
                              void* d_out, int out_size, void* d_ws, size_t ws_size,
                              hipStream_t stream) {
  const float* graph = (const float*)d_in[0];
  const float* text  = (const float*)d_in[1];
  const float* W     = (const float*)d_in[2];
  const float* bias  = (const float*)d_in[3];
  float* out = (float*)d_out;
  char* ws = (char*)d_ws;

  u16*  tH     = (u16*)(ws);                 // 8192*384*2  = 6291456
  u16*  gHi    = (u16*)(ws + 6291456);       // 8192*256*2  = 4194304
  u16*  wHi    = (u16*)(ws + 10485760);      // 384*256*2   = 196608
  float* g     = (float*)(ws + 10682368);    // 8192*384*4  = 12582912
  int*  gMax   = (int*)(ws + 23265280);      // 32768
  int*  gMin   = (int*)(ws + 23298048);      // 32768
  float* losses = (float*)(ws + 23330816);   // 32768

  prep_text<<<dim3(2048), dim3(256), 0, stream>>>(text, tH, gMax, gMin);
  cvt_all<<<dim3(2144), dim3(256), 0, stream>>>(graph, W, gHi, wHi);
  gemm1<<<dim3(64, 3), dim3(256), 0, stream>>>(gHi, wHi, bias, g);
  simk<<<dim3(1056), dim3(256), 0, stream>>>(tH, gMax, gMin);
  loss_rows<<<dim3(2048), dim3(256), 0, stream>>>(g, gMax, gMin, losses);
  final_reduce<<<dim3(1), dim3(256), 0, stream>>>(losses, out);
}